// Round 18
// baseline (292.976 us; speedup 1.0000x reference)
//
#include <hip/hip_runtime.h>

#define NB 8192
#define NT 512

typedef unsigned int u32;
typedef unsigned short u16;
typedef float f32x4 __attribute__((ext_vector_type(4)));
typedef u32 u32x2 __attribute__((ext_vector_type(2)));
typedef _Float16 h16x2 __attribute__((ext_vector_type(2)));

__device__ __forceinline__ float rcp_(float x){ return __builtin_amdgcn_rcpf(x); }
__device__ __forceinline__ float exp2_(float x){ return __builtin_amdgcn_exp2f(x); }
__device__ __forceinline__ float tanh_(float x){ return 1.0f - 2.0f*rcp_(1.0f + exp2_(2.88539008177792681f*x)); }
__device__ __forceinline__ float sigm(float x){ return rcp_(1.0f + exp2_(-1.44269504088896341f*x)); }

#define PINF(v)  asm volatile("" : "+v"(v))

// Broadcast lane (group8_base + J) to all 8 lanes of the group (validated R17).
template<int J>
__device__ __forceinline__ float swzbc(float x){
    return __int_as_float(__builtin_amdgcn_ds_swizzle(__float_as_int(x), (J<<5)|0x18));
}

__device__ __forceinline__ float upkh(u16 v){ _Float16 h; __builtin_memcpy(&h,&v,2); return (float)h; }
__device__ __forceinline__ float upk_lo(u32 v){ return upkh((u16)(v&0xffffu)); }
__device__ __forceinline__ float upk_hi(u32 v){ return upkh((u16)(v>>16)); }
__device__ __forceinline__ u32 pkrtz(float a, float b){
    auto p = __builtin_amdgcn_cvt_pkrtz(a, b);
    return __builtin_bit_cast(u32, p);
}
__device__ __forceinline__ float dot2f(h16x2 a, h16x2 b, float c){
#if __has_builtin(__builtin_amdgcn_fdot2)
    return __builtin_amdgcn_fdot2(a, b, c, false);
#else
    return fmaf((float)a.x, (float)b.x, fmaf((float)a.y, (float)b.y, c));
#endif
}
__device__ __forceinline__ float dot2u(u32 w, u32 d, float c){
    return dot2f(__builtin_bit_cast(h16x2, w), __builtin_bit_cast(h16x2, d), c);
}

// ---------------------------------------------------------------------------
// Lane-local-gates layout (validated R17): 8 lanes/seq; lane j owns hidden
// unit jj=min(j,j-2) and computes all 4 gates locally. Cross-lane per step =
// 6 swzbc + 3 pkrtz. Buffer per (t-pair, seq): 6 dwords
//   [h01@E, h01@O, h23@E, h23@O, h45@E, h45@O]  (fp16 pairs)
// ---------------------------------------------------------------------------

// Merged-direction layer 0: ONE wave handles fwd AND bwd chains of its seqs
// (2 independent recurrence chains per wave -> ILP covers latency at 1/SIMD).
// 1024 blocks x 64 threads = 1024 waves.
__global__ __launch_bounds__(64)
__attribute__((amdgpu_waves_per_eu(1,1)))
void lstm_l0m(
    const float* __restrict__ x,
    const float* __restrict__ h0, const float* __restrict__ c0,
    const float* __restrict__ Wf, const float* __restrict__ Uf, const float* __restrict__ bf,
    const float* __restrict__ Wb, const float* __restrict__ Ub, const float* __restrict__ bbv,
    char* __restrict__ fbuf, char* __restrict__ bbuf)
{
    const int l  = threadIdx.x;
    const int j  = l & 7;
    const int jj = (j < 6) ? j : (j - 2);
    const int b  = blockIdx.x*8 + (l >> 3);

    u32 wdF[4][6], wdB[4][6]; float cEbF[4], cEbB[4];
#pragma unroll
    for (int g=0; g<4; ++g){
        const int row = g*6 + jj;
        const float cs = (g==2) ? -2.88539008177792681f : -1.44269504088896341f;
#pragma unroll
        for (int k=0;k<3;++k){
            wdF[g][k]   = pkrtz(cs*Wf[row*6+2*k], cs*Wf[row*6+2*k+1]);
            wdF[g][3+k] = pkrtz(cs*Uf[row*6+2*k], cs*Uf[row*6+2*k+1]);
            wdB[g][k]   = pkrtz(cs*Wb[row*6+2*k], cs*Wb[row*6+2*k+1]);
            wdB[g][3+k] = pkrtz(cs*Ub[row*6+2*k], cs*Ub[row*6+2*k+1]);
        }
        cEbF[g] = cs * bf[row];
        cEbB[g] = cs * bbv[row];
    }
#pragma unroll
    for (int g=0; g<4; ++g){
#pragma unroll
        for (int k=0;k<6;++k){ PINF(wdF[g][k]); PINF(wdB[g][k]); }
        PINF(cEbF[g]); PINF(cEbB[g]);
    }

    float ccF = c0[0*(NB*6) + b*6 + jj];
    float hnF = h0[0*(NB*6) + b*6 + jj];
    float ccB = c0[1*(NB*6) + b*6 + jj];
    float hnB = h0[1*(NB*6) + b*6 + jj];
    u32 dF01,dF23,dF45, dB01,dB23,dB45;
    {
        float t0=swzbc<0>(hnF), t1=swzbc<1>(hnF), t2=swzbc<2>(hnF),
              t3=swzbc<3>(hnF), t4=swzbc<4>(hnF), t5=swzbc<5>(hnF);
        dF01=pkrtz(t0,t1); dF23=pkrtz(t2,t3); dF45=pkrtz(t4,t5);
        t0=swzbc<0>(hnB); t1=swzbc<1>(hnB); t2=swzbc<2>(hnB);
        t3=swzbc<3>(hnB); t4=swzbc<4>(hnB); t5=swzbc<5>(hnB);
        dB01=pkrtz(t0,t1); dB23=pkrtz(t2,t3); dB45=pkrtz(t4,t5);
    }

    const char* xb = (const char*)(x + (size_t)b*(NT*6));
    char* ofb = fbuf + (size_t)b*24 + j*8;
    char* obb = bbuf + (size_t)b*24 + j*8;
    const size_t tstr = (size_t)NB*24;

    auto STEPF = [&](u32 px0, u32 px1, u32 px2){
        float z0=cEbF[0], z1=cEbF[1], z2=cEbF[2], z3=cEbF[3];
        z0=dot2u(wdF[0][0],px0,z0); z0=dot2u(wdF[0][1],px1,z0); z0=dot2u(wdF[0][2],px2,z0);
        z0=dot2u(wdF[0][3],dF01,z0); z0=dot2u(wdF[0][4],dF23,z0); z0=dot2u(wdF[0][5],dF45,z0);
        z1=dot2u(wdF[1][0],px0,z1); z1=dot2u(wdF[1][1],px1,z1); z1=dot2u(wdF[1][2],px2,z1);
        z1=dot2u(wdF[1][3],dF01,z1); z1=dot2u(wdF[1][4],dF23,z1); z1=dot2u(wdF[1][5],dF45,z1);
        z2=dot2u(wdF[2][0],px0,z2); z2=dot2u(wdF[2][1],px1,z2); z2=dot2u(wdF[2][2],px2,z2);
        z2=dot2u(wdF[2][3],dF01,z2); z2=dot2u(wdF[2][4],dF23,z2); z2=dot2u(wdF[2][5],dF45,z2);
        z3=dot2u(wdF[3][0],px0,z3); z3=dot2u(wdF[3][1],px1,z3); z3=dot2u(wdF[3][2],px2,z3);
        z3=dot2u(wdF[3][3],dF01,z3); z3=dot2u(wdF[3][4],dF23,z3); z3=dot2u(wdF[3][5],dF45,z3);
        const float iv = rcp_(1.0f + exp2_(z0));
        const float fv = rcp_(1.0f + exp2_(z1));
        const float gv = fmaf(2.0f, rcp_(1.0f + exp2_(z2)), -1.0f);
        const float ov = rcp_(1.0f + exp2_(z3));
        ccF = fmaf(fv, ccF, iv*gv);
        hnF = ov * tanh_(ccF);
        const float t0=swzbc<0>(hnF), t1=swzbc<1>(hnF), t2=swzbc<2>(hnF),
                    t3=swzbc<3>(hnF), t4=swzbc<4>(hnF), t5=swzbc<5>(hnF);
        dF01=pkrtz(t0,t1); dF23=pkrtz(t2,t3); dF45=pkrtz(t4,t5);
    };
    auto STEPB = [&](u32 px0, u32 px1, u32 px2){
        float z0=cEbB[0], z1=cEbB[1], z2=cEbB[2], z3=cEbB[3];
        z0=dot2u(wdB[0][0],px0,z0); z0=dot2u(wdB[0][1],px1,z0); z0=dot2u(wdB[0][2],px2,z0);
        z0=dot2u(wdB[0][3],dB01,z0); z0=dot2u(wdB[0][4],dB23,z0); z0=dot2u(wdB[0][5],dB45,z0);
        z1=dot2u(wdB[1][0],px0,z1); z1=dot2u(wdB[1][1],px1,z1); z1=dot2u(wdB[1][2],px2,z1);
        z1=dot2u(wdB[1][3],dB01,z1); z1=dot2u(wdB[1][4],dB23,z1); z1=dot2u(wdB[1][5],dB45,z1);
        z2=dot2u(wdB[2][0],px0,z2); z2=dot2u(wdB[2][1],px1,z2); z2=dot2u(wdB[2][2],px2,z2);
        z2=dot2u(wdB[2][3],dB01,z2); z2=dot2u(wdB[2][4],dB23,z2); z2=dot2u(wdB[2][5],dB45,z2);
        z3=dot2u(wdB[3][0],px0,z3); z3=dot2u(wdB[3][1],px1,z3); z3=dot2u(wdB[3][2],px2,z3);
        z3=dot2u(wdB[3][3],dB01,z3); z3=dot2u(wdB[3][4],dB23,z3); z3=dot2u(wdB[3][5],dB45,z3);
        const float iv = rcp_(1.0f + exp2_(z0));
        const float fv = rcp_(1.0f + exp2_(z1));
        const float gv = fmaf(2.0f, rcp_(1.0f + exp2_(z2)), -1.0f);
        const float ov = rcp_(1.0f + exp2_(z3));
        ccB = fmaf(fv, ccB, iv*gv);
        hnB = ov * tanh_(ccB);
        const float t0=swzbc<0>(hnB), t1=swzbc<1>(hnB), t2=swzbc<2>(hnB),
                    t3=swzbc<3>(hnB), t4=swzbc<4>(hnB), t5=swzbc<5>(hnB);
        dB01=pkrtz(t0,t1); dB23=pkrtz(t2,t3); dB45=pkrtz(t4,t5);
    };

    f32x4 xFA[3], xFB[3], xBA[3], xBB[3];
    auto ldg = [&](int p, f32x4* d){
        const f32x4* q = (const f32x4*)(xb + (size_t)p*48);
        d[0]=q[0]; d[1]=q[1]; d[2]=q[2];
    };

    // GROUP: one pair (2 steps) of each direction, interleaved for ILP.
    // fwd processes t=2pf,2pf+1 ascending; bwd processes t=2pb+1,2pb descending.
    auto GROUP = [&](const f32x4* fd, const f32x4* bd, int pf, int pb){
        STEPF(pkrtz(fd[0].x,fd[0].y), pkrtz(fd[0].z,fd[0].w), pkrtz(fd[1].x,fd[1].y));
        const u32 fe0=dF01, fe1=dF23, fe2=dF45;
        STEPB(pkrtz(bd[1].z,bd[1].w), pkrtz(bd[2].x,bd[2].y), pkrtz(bd[2].z,bd[2].w));
        const u32 bo0=dB01, bo1=dB23, bo2=dB45;
        STEPF(pkrtz(fd[1].z,fd[1].w), pkrtz(fd[2].x,fd[2].y), pkrtz(fd[2].z,fd[2].w));
        STEPB(pkrtz(bd[0].x,bd[0].y), pkrtz(bd[0].z,bd[0].w), pkrtz(bd[1].x,bd[1].y));
        if (j < 3){
            const u32 fe = (j==0)?fe0:((j==1)?fe1:fe2);
            const u32 fo = (j==0)?dF01:((j==1)?dF23:dF45);
            u32x2 vf; vf.x=fe; vf.y=fo;
            *(u32x2*)(ofb + (size_t)pf*tstr) = vf;
            const u32 be = (j==0)?dB01:((j==1)?dB23:dB45);
            const u32 bo = (j==0)?bo0:((j==1)?bo1:bo2);
            u32x2 vb; vb.x=be; vb.y=bo;
            *(u32x2*)(obb + (size_t)pb*tstr) = vb;
        }
    };

    ldg(0, xFA); ldg(1, xFB); ldg(NT/2-1, xBA); ldg(NT/2-2, xBB);
    for (int it=0; it<NT/2; it+=2){
        GROUP(xFA, xBA, it, NT/2-1-it);
        { int pn=it+2;       if (pn>NT/2-1) pn=NT/2-1; ldg(pn, xFA);
          int qn=NT/2-3-it;  if (qn<0) qn=0;           ldg(qn, xBA); }
        GROUP(xFB, xBB, it+1, NT/2-2-it);
        { int pn=it+3;       if (pn>NT/2-1) pn=NT/2-1; ldg(pn, xFB);
          int qn=NT/2-4-it;  if (qn<0) qn=0;           ldg(qn, xBB); }
    }
}

// Layer 1 forward scan + r1 single step + FC head (unchanged from R17 pass).
__global__ __launch_bounds__(64)
__attribute__((amdgpu_waves_per_eu(1,1)))
void lstm_l1v2(
    const char* __restrict__ fbuf, const char* __restrict__ bbuf,
    const float* __restrict__ h0, const float* __restrict__ c0,
    const float* __restrict__ W1f, const float* __restrict__ U1f, const float* __restrict__ b1f,
    const float* __restrict__ W1b, const float* __restrict__ U1b, const float* __restrict__ b1b,
    const float* __restrict__ fcw, const float* __restrict__ fcb,
    float* __restrict__ out)
{
    const int l  = threadIdx.x;
    const int j  = l & 7;
    const int jj = (j < 6) ? j : (j - 2);
    const int b  = blockIdx.x*8 + (l >> 3);

    u32 wd1[4][9]; float cEb[4];
#pragma unroll
    for (int g=0; g<4; ++g){
        const int row = g*6 + jj;
        const float cs = (g==2) ? -2.88539008177792681f : -1.44269504088896341f;
#pragma unroll
        for (int k=0;k<3;++k) wd1[g][k]   = pkrtz(cs*W1f[row*12+2*k],   cs*W1f[row*12+2*k+1]);
#pragma unroll
        for (int k=0;k<3;++k) wd1[g][3+k] = pkrtz(cs*W1f[row*12+6+2*k], cs*W1f[row*12+6+2*k+1]);
#pragma unroll
        for (int k=0;k<3;++k) wd1[g][6+k] = pkrtz(cs*U1f[row*6+2*k],    cs*U1f[row*6+2*k+1]);
        cEb[g] = cs * b1f[row];
    }
#pragma unroll
    for (int g=0; g<4; ++g){
#pragma unroll
        for (int k=0;k<9;++k) PINF(wd1[g][k]);
        PINF(cEb[g]);
    }

    float cc = c0[2*(NB*6) + b*6 + jj];
    float hn = h0[2*(NB*6) + b*6 + jj];
    u32 d01, d23, d45;
    {
        const float t0=swzbc<0>(hn), t1=swzbc<1>(hn), t2=swzbc<2>(hn),
                    t3=swzbc<3>(hn), t4=swzbc<4>(hn), t5=swzbc<5>(hn);
        d01=pkrtz(t0,t1); d23=pkrtz(t2,t3); d45=pkrtz(t4,t5);
    }

    const char* fp = fbuf + (size_t)b*24;
    const char* rp = bbuf + (size_t)b*24;
    const size_t tstr = (size_t)NB*24;

    auto STEP = [&](u32 f0d, u32 f1d, u32 f2d, u32 r0d, u32 r1d, u32 r2d){
        float z0=cEb[0], z1=cEb[1], z2=cEb[2], z3=cEb[3];
        z0=dot2u(wd1[0][0],f0d,z0); z0=dot2u(wd1[0][1],f1d,z0); z0=dot2u(wd1[0][2],f2d,z0);
        z0=dot2u(wd1[0][3],r0d,z0); z0=dot2u(wd1[0][4],r1d,z0); z0=dot2u(wd1[0][5],r2d,z0);
        z0=dot2u(wd1[0][6],d01,z0); z0=dot2u(wd1[0][7],d23,z0); z0=dot2u(wd1[0][8],d45,z0);
        z1=dot2u(wd1[1][0],f0d,z1); z1=dot2u(wd1[1][1],f1d,z1); z1=dot2u(wd1[1][2],f2d,z1);
        z1=dot2u(wd1[1][3],r0d,z1); z1=dot2u(wd1[1][4],r1d,z1); z1=dot2u(wd1[1][5],r2d,z1);
        z1=dot2u(wd1[1][6],d01,z1); z1=dot2u(wd1[1][7],d23,z1); z1=dot2u(wd1[1][8],d45,z1);
        z2=dot2u(wd1[2][0],f0d,z2); z2=dot2u(wd1[2][1],f1d,z2); z2=dot2u(wd1[2][2],f2d,z2);
        z2=dot2u(wd1[2][3],r0d,z2); z2=dot2u(wd1[2][4],r1d,z2); z2=dot2u(wd1[2][5],r2d,z2);
        z2=dot2u(wd1[2][6],d01,z2); z2=dot2u(wd1[2][7],d23,z2); z2=dot2u(wd1[2][8],d45,z2);
        z3=dot2u(wd1[3][0],f0d,z3); z3=dot2u(wd1[3][1],f1d,z3); z3=dot2u(wd1[3][2],f2d,z3);
        z3=dot2u(wd1[3][3],r0d,z3); z3=dot2u(wd1[3][4],r1d,z3); z3=dot2u(wd1[3][5],r2d,z3);
        z3=dot2u(wd1[3][6],d01,z3); z3=dot2u(wd1[3][7],d23,z3); z3=dot2u(wd1[3][8],d45,z3);
        const float iv = rcp_(1.0f + exp2_(z0));
        const float fv = rcp_(1.0f + exp2_(z1));
        const float gv = fmaf(2.0f, rcp_(1.0f + exp2_(z2)), -1.0f);
        const float ov = rcp_(1.0f + exp2_(z3));
        cc = fmaf(fv, cc, iv*gv);
        hn = ov * tanh_(cc);
        const float t0=swzbc<0>(hn), t1=swzbc<1>(hn), t2=swzbc<2>(hn),
                    t3=swzbc<3>(hn), t4=swzbc<4>(hn), t5=swzbc<5>(hn);
        d01=pkrtz(t0,t1); d23=pkrtz(t2,t3); d45=pkrtz(t4,t5);
    };

    u32x2 FA[3], RA[3], FB[3], RB[3];
    auto ldp = [&](int p, u32x2* F, u32x2* R){
        const u32x2* f = (const u32x2*)(fp + (size_t)p*tstr);
        const u32x2* r = (const u32x2*)(rp + (size_t)p*tstr);
        F[0]=f[0]; F[1]=f[1]; F[2]=f[2];
        R[0]=r[0]; R[1]=r[1]; R[2]=r[2];
    };
    auto GROUP = [&](const u32x2* F, const u32x2* R){
        STEP(F[0].x, F[1].x, F[2].x, R[0].x, R[1].x, R[2].x);
        STEP(F[0].y, F[1].y, F[2].y, R[0].y, R[1].y, R[2].y);
    };

    ldp(0, FA, RA); ldp(1, FB, RB);
    for (int p=0; p<NT/2; p+=2){
        GROUP(FA, RA);
        { int pn=p+2; pn = pn>NT/2-1?NT/2-1:pn; ldp(pn, FA, RA); }
        GROUP(FB, RB);
        { int pn=p+3; pn = pn>NT/2-1?NT/2-1:pn; ldp(pn, FB, RB); }
    }

    // ---- l0[511] as f32 (odd dwords of pair 255) ----
    float v[12];
    {
        const char* f255 = fp + (size_t)(NT/2-1)*tstr;
        const char* r255 = rp + (size_t)(NT/2-1)*tstr;
#pragma unroll
        for (int k=0;k<3;++k){
            const u32 fd = *(const u32*)(f255 + k*8 + 4);
            const u32 rd = *(const u32*)(r255 + k*8 + 4);
            v[2*k]   = upk_lo(fd);  v[2*k+1]   = upk_hi(fd);
            v[6+2*k] = upk_lo(rd);  v[6+2*k+1] = upk_hi(rd);
        }
    }

    // ---- r1: single reverse-direction step at t = NT-1 (f32 math) ----
    const int base3 = 3*(NB*6) + b*6;
    float hr6[6];
#pragma unroll
    for (int k=0;k<6;++k) hr6[k] = h0[base3 + k];
    float cr = c0[base3 + jj];

    float zr[4];
#pragma unroll
    for (int g=0; g<4; ++g){
        const int row = g*6 + jj;
        float acc = b1b[row];
#pragma unroll
        for (int k=0;k<12;++k) acc = fmaf(W1b[row*12+k], v[k], acc);
#pragma unroll
        for (int k=0;k<6;++k)  acc = fmaf(U1b[row*6+k], hr6[k], acc);
        zr[g] = acc;
    }
    {
        const float iv = sigm(zr[0]);
        const float fv = sigm(zr[1]);
        const float gv = tanh_(zr[2]);
        cr = fmaf(fv, cr, iv*gv);
    }
    const float hrv = sigm(zr[3]) * tanh_(cr);

    // ---- head ----
    float u[12];
    u[0]=fmaxf(swzbc<0>(hn),0.f); u[1]=fmaxf(swzbc<1>(hn),0.f); u[2]=fmaxf(swzbc<2>(hn),0.f);
    u[3]=fmaxf(swzbc<3>(hn),0.f); u[4]=fmaxf(swzbc<4>(hn),0.f); u[5]=fmaxf(swzbc<5>(hn),0.f);
    u[6]=fmaxf(swzbc<0>(hrv),0.f); u[7]=fmaxf(swzbc<1>(hrv),0.f); u[8]=fmaxf(swzbc<2>(hrv),0.f);
    u[9]=fmaxf(swzbc<3>(hrv),0.f); u[10]=fmaxf(swzbc<4>(hrv),0.f); u[11]=fmaxf(swzbc<5>(hrv),0.f);
    if (j < 6){
        float acc = fcb[j];
#pragma unroll
        for (int k=0;k<12;++k) acc = fmaf(fcw[j*12+k], u[k], acc);
        out[b*6 + j] = acc;
    }
}

extern "C" void kernel_launch(void* const* d_in, const int* in_sizes, int n_in,
                              void* d_out, int out_size, void* d_ws, size_t ws_size,
                              hipStream_t stream)
{
    (void)in_sizes; (void)n_in; (void)out_size; (void)ws_size;
    const float* x    = (const float*)d_in[0];
    const float* h0   = (const float*)d_in[1];
    const float* c0   = (const float*)d_in[2];
    const float* W0f  = (const float*)d_in[3];
    const float* U0f  = (const float*)d_in[4];
    const float* b0f  = (const float*)d_in[5];
    const float* W0b  = (const float*)d_in[6];
    const float* U0b  = (const float*)d_in[7];
    const float* b0b  = (const float*)d_in[8];
    const float* W1f  = (const float*)d_in[9];
    const float* U1f  = (const float*)d_in[10];
    const float* b1f  = (const float*)d_in[11];
    const float* W1b  = (const float*)d_in[12];
    const float* U1b  = (const float*)d_in[13];
    const float* b1b  = (const float*)d_in[14];
    const float* fcw  = (const float*)d_in[15];
    const float* fcb  = (const float*)d_in[16];
    float* out = (float*)d_out;
    char* ws = (char*)d_ws;

    char* fbuf = ws;
    char* bbuf = ws + (size_t)(NT/2)*NB*24;   // 2 x 50.3 MB

    lstm_l0m<<<dim3(1024), dim3(64), 0, stream>>>(x, h0, c0, W0f, U0f, b0f, W0b, U0b, b0b, fbuf, bbuf);
    lstm_l1v2<<<dim3(1024), dim3(64), 0, stream>>>(fbuf, bbuf, h0, c0,
        W1f, U1f, b1f, W1b, U1b, b1b, fcw, fcb, out);
}

// Round 19
// 286.540 us; speedup vs baseline: 1.0225x; 1.0225x over previous
//
#include <hip/hip_runtime.h>

#define NB 8192
#define NT 512

typedef unsigned int u32;
typedef unsigned short u16;
typedef float f32x4 __attribute__((ext_vector_type(4)));
typedef u32 u32x2 __attribute__((ext_vector_type(2)));
typedef _Float16 h16x2 __attribute__((ext_vector_type(2)));

__device__ __forceinline__ float rcp_(float x){ return __builtin_amdgcn_rcpf(x); }
__device__ __forceinline__ float exp2_(float x){ return __builtin_amdgcn_exp2f(x); }
__device__ __forceinline__ float tanh_(float x){ return 1.0f - 2.0f*rcp_(1.0f + exp2_(2.88539008177792681f*x)); }
__device__ __forceinline__ float sigm(float x){ return rcp_(1.0f + exp2_(-1.44269504088896341f*x)); }

#define PINF(v)  asm volatile("" : "+v"(v))

// Broadcast lane (group8_base + J) to all 8 lanes of the group (validated R17).
template<int J>
__device__ __forceinline__ float swzbc(float x){
    return __int_as_float(__builtin_amdgcn_ds_swizzle(__float_as_int(x), (J<<5)|0x18));
}

__device__ __forceinline__ float upkh(u16 v){ _Float16 h; __builtin_memcpy(&h,&v,2); return (float)h; }
__device__ __forceinline__ float upk_lo(u32 v){ return upkh((u16)(v&0xffffu)); }
__device__ __forceinline__ float upk_hi(u32 v){ return upkh((u16)(v>>16)); }
__device__ __forceinline__ u32 pkrtz(float a, float b){
    auto p = __builtin_amdgcn_cvt_pkrtz(a, b);
    return __builtin_bit_cast(u32, p);
}
__device__ __forceinline__ float dot2f(h16x2 a, h16x2 b, float c){
#if __has_builtin(__builtin_amdgcn_fdot2)
    return __builtin_amdgcn_fdot2(a, b, c, false);
#else
    return fmaf((float)a.x, (float)b.x, fmaf((float)a.y, (float)b.y, c));
#endif
}
__device__ __forceinline__ float dot2u(u32 w, u32 d, float c){
    return dot2f(__builtin_bit_cast(h16x2, w), __builtin_bit_cast(h16x2, d), c);
}

// ---------------------------------------------------------------------------
// Lane-local-gates layout (validated R17): 8 lanes/seq; lane j owns hidden
// unit jj and computes all 4 gates locally. Cross-lane per step = 6 swzbc +
// 3 pkrtz. bbuf per (t-pair, seq): [r01@E, r01@O, r23@E, r23@O, r45@E, r45@O]
// ---------------------------------------------------------------------------

// K1: layer-0 BACKWARD only. 1024 blocks x 64 = 1024 waves, 1 chain each.
__global__ __launch_bounds__(64)
__attribute__((amdgpu_waves_per_eu(1,1)))
void lstm_l0b(
    const float* __restrict__ x,
    const float* __restrict__ h0, const float* __restrict__ c0,
    const float* __restrict__ Wb, const float* __restrict__ Ub, const float* __restrict__ bbv,
    char* __restrict__ bbuf)
{
    const int l  = threadIdx.x;
    const int j  = l & 7;
    const int jj = (j < 6) ? j : (j - 2);
    const int b  = blockIdx.x*8 + (l >> 3);

    u32 wd[4][6]; float cEb[4];
#pragma unroll
    for (int g=0; g<4; ++g){
        const int row = g*6 + jj;
        const float cs = (g==2) ? -2.88539008177792681f : -1.44269504088896341f;
#pragma unroll
        for (int k=0;k<3;++k){
            wd[g][k]   = pkrtz(cs*Wb[row*6+2*k], cs*Wb[row*6+2*k+1]);
            wd[g][3+k] = pkrtz(cs*Ub[row*6+2*k], cs*Ub[row*6+2*k+1]);
        }
        cEb[g] = cs * bbv[row];
    }
#pragma unroll
    for (int g=0; g<4; ++g){
#pragma unroll
        for (int k=0;k<6;++k) PINF(wd[g][k]);
        PINF(cEb[g]);
    }

    float cc = c0[1*(NB*6) + b*6 + jj];
    float hn = h0[1*(NB*6) + b*6 + jj];
    u32 d01, d23, d45;
    {
        const float t0=swzbc<0>(hn), t1=swzbc<1>(hn), t2=swzbc<2>(hn),
                    t3=swzbc<3>(hn), t4=swzbc<4>(hn), t5=swzbc<5>(hn);
        d01=pkrtz(t0,t1); d23=pkrtz(t2,t3); d45=pkrtz(t4,t5);
    }

    const char* xb = (const char*)(x + (size_t)b*(NT*6));
    char* obase = bbuf + (size_t)b*24 + j*8;
    const size_t tstr = (size_t)NB*24;

    auto STEP = [&](u32 px0, u32 px1, u32 px2){
        float z0=cEb[0], z1=cEb[1], z2=cEb[2], z3=cEb[3];
        z0=dot2u(wd[0][0],px0,z0); z0=dot2u(wd[0][1],px1,z0); z0=dot2u(wd[0][2],px2,z0);
        z0=dot2u(wd[0][3],d01,z0); z0=dot2u(wd[0][4],d23,z0); z0=dot2u(wd[0][5],d45,z0);
        z1=dot2u(wd[1][0],px0,z1); z1=dot2u(wd[1][1],px1,z1); z1=dot2u(wd[1][2],px2,z1);
        z1=dot2u(wd[1][3],d01,z1); z1=dot2u(wd[1][4],d23,z1); z1=dot2u(wd[1][5],d45,z1);
        z2=dot2u(wd[2][0],px0,z2); z2=dot2u(wd[2][1],px1,z2); z2=dot2u(wd[2][2],px2,z2);
        z2=dot2u(wd[2][3],d01,z2); z2=dot2u(wd[2][4],d23,z2); z2=dot2u(wd[2][5],d45,z2);
        z3=dot2u(wd[3][0],px0,z3); z3=dot2u(wd[3][1],px1,z3); z3=dot2u(wd[3][2],px2,z3);
        z3=dot2u(wd[3][3],d01,z3); z3=dot2u(wd[3][4],d23,z3); z3=dot2u(wd[3][5],d45,z3);
        const float iv = rcp_(1.0f + exp2_(z0));
        const float fv = rcp_(1.0f + exp2_(z1));
        const float gv = fmaf(2.0f, rcp_(1.0f + exp2_(z2)), -1.0f);
        const float ov = rcp_(1.0f + exp2_(z3));
        cc = fmaf(fv, cc, iv*gv);
        hn = ov * tanh_(cc);
        const float t0=swzbc<0>(hn), t1=swzbc<1>(hn), t2=swzbc<2>(hn),
                    t3=swzbc<3>(hn), t4=swzbc<4>(hn), t5=swzbc<5>(hn);
        d01=pkrtz(t0,t1); d23=pkrtz(t2,t3); d45=pkrtz(t4,t5);
    };

    f32x4 xA[3], xB[3];
    auto ldg = [&](int p, f32x4* d){
        const f32x4* q = (const f32x4*)(xb + (size_t)p*48);
        d[0]=q[0]; d[1]=q[1]; d[2]=q[2];
    };

    auto GROUP = [&](const f32x4* d, int p){
        // bwd: odd step (t=2p+1) first, then even (t=2p)
        STEP(pkrtz(d[1].z,d[1].w), pkrtz(d[2].x,d[2].y), pkrtz(d[2].z,d[2].w));
        const u32 o0=d01, o1=d23, o2=d45;
        STEP(pkrtz(d[0].x,d[0].y), pkrtz(d[0].z,d[0].w), pkrtz(d[1].x,d[1].y));
        if (j < 3){
            const u32 se = (j==0)?d01:((j==1)?d23:d45);
            const u32 so = (j==0)?o0:((j==1)?o1:o2);
            u32x2 v; v.x=se; v.y=so;
            *(u32x2*)(obase + (size_t)p*tstr) = v;
        }
    };

    ldg(NT/2-1, xA); ldg(NT/2-2, xB);
    for (int it=0; it<NT/2; it+=2){
        GROUP(xA, NT/2-1-it);
        { int qn=NT/2-3-it; if (qn<0) qn=0; ldg(qn, xA); }
        GROUP(xB, NT/2-2-it);
        { int qn=NT/2-4-it; if (qn<0) qn=0; ldg(qn, xB); }
    }
}

// K2: fused f0 + f1 (both forward). f0's broadcast dwords feed f1's dense
// directly; NO stores in the main loop. + r1 single step + FC head.
// 1024 blocks x 64 = 1024 waves, 2 pipelined chains each.
__global__ __launch_bounds__(64)
__attribute__((amdgpu_waves_per_eu(1,1)))
void lstm_f01(
    const char* __restrict__ bbuf,
    const float* __restrict__ x,
    const float* __restrict__ h0, const float* __restrict__ c0,
    const float* __restrict__ W0f, const float* __restrict__ U0f, const float* __restrict__ b0f,
    const float* __restrict__ W1f, const float* __restrict__ U1f, const float* __restrict__ b1f,
    const float* __restrict__ W1b, const float* __restrict__ U1b, const float* __restrict__ b1b,
    const float* __restrict__ fcw, const float* __restrict__ fcb,
    float* __restrict__ out)
{
    const int l  = threadIdx.x;
    const int j  = l & 7;
    const int jj = (j < 6) ? j : (j - 2);
    const int b  = blockIdx.x*8 + (l >> 3);

    // f0 weights
    u32 wd0[4][6]; float cEb0[4];
    // f1 weights: k0..2 -> W1f cols0-5 (f0-h pairs), k3..5 -> W1f cols6-11 (r0),
    // k6..8 -> U1f (own h1 pairs)
    u32 wd1[4][9]; float cEb1[4];
#pragma unroll
    for (int g=0; g<4; ++g){
        const int row = g*6 + jj;
        const float cs = (g==2) ? -2.88539008177792681f : -1.44269504088896341f;
#pragma unroll
        for (int k=0;k<3;++k){
            wd0[g][k]   = pkrtz(cs*W0f[row*6+2*k], cs*W0f[row*6+2*k+1]);
            wd0[g][3+k] = pkrtz(cs*U0f[row*6+2*k], cs*U0f[row*6+2*k+1]);
            wd1[g][k]   = pkrtz(cs*W1f[row*12+2*k],   cs*W1f[row*12+2*k+1]);
            wd1[g][3+k] = pkrtz(cs*W1f[row*12+6+2*k], cs*W1f[row*12+6+2*k+1]);
            wd1[g][6+k] = pkrtz(cs*U1f[row*6+2*k],    cs*U1f[row*6+2*k+1]);
        }
        cEb0[g] = cs * b0f[row];
        cEb1[g] = cs * b1f[row];
    }
#pragma unroll
    for (int g=0; g<4; ++g){
#pragma unroll
        for (int k=0;k<6;++k) PINF(wd0[g][k]);
#pragma unroll
        for (int k=0;k<9;++k) PINF(wd1[g][k]);
        PINF(cEb0[g]); PINF(cEb1[g]);
    }

    float cc0 = c0[0*(NB*6) + b*6 + jj];
    float hn0 = h0[0*(NB*6) + b*6 + jj];
    float cc1 = c0[2*(NB*6) + b*6 + jj];
    float hn1 = h0[2*(NB*6) + b*6 + jj];
    u32 d001,d023,d045, d101,d123,d145;
    {
        float t0=swzbc<0>(hn0), t1=swzbc<1>(hn0), t2=swzbc<2>(hn0),
              t3=swzbc<3>(hn0), t4=swzbc<4>(hn0), t5=swzbc<5>(hn0);
        d001=pkrtz(t0,t1); d023=pkrtz(t2,t3); d045=pkrtz(t4,t5);
        t0=swzbc<0>(hn1); t1=swzbc<1>(hn1); t2=swzbc<2>(hn1);
        t3=swzbc<3>(hn1); t4=swzbc<4>(hn1); t5=swzbc<5>(hn1);
        d101=pkrtz(t0,t1); d123=pkrtz(t2,t3); d145=pkrtz(t4,t5);
    }

    const char* xb = (const char*)(x + (size_t)b*(NT*6));
    const char* rp = bbuf + (size_t)b*24;
    const size_t tstr = (size_t)NB*24;

    auto STEP0 = [&](u32 px0, u32 px1, u32 px2){
        float z0=cEb0[0], z1=cEb0[1], z2=cEb0[2], z3=cEb0[3];
        z0=dot2u(wd0[0][0],px0,z0); z0=dot2u(wd0[0][1],px1,z0); z0=dot2u(wd0[0][2],px2,z0);
        z0=dot2u(wd0[0][3],d001,z0); z0=dot2u(wd0[0][4],d023,z0); z0=dot2u(wd0[0][5],d045,z0);
        z1=dot2u(wd0[1][0],px0,z1); z1=dot2u(wd0[1][1],px1,z1); z1=dot2u(wd0[1][2],px2,z1);
        z1=dot2u(wd0[1][3],d001,z1); z1=dot2u(wd0[1][4],d023,z1); z1=dot2u(wd0[1][5],d045,z1);
        z2=dot2u(wd0[2][0],px0,z2); z2=dot2u(wd0[2][1],px1,z2); z2=dot2u(wd0[2][2],px2,z2);
        z2=dot2u(wd0[2][3],d001,z2); z2=dot2u(wd0[2][4],d023,z2); z2=dot2u(wd0[2][5],d045,z2);
        z3=dot2u(wd0[3][0],px0,z3); z3=dot2u(wd0[3][1],px1,z3); z3=dot2u(wd0[3][2],px2,z3);
        z3=dot2u(wd0[3][3],d001,z3); z3=dot2u(wd0[3][4],d023,z3); z3=dot2u(wd0[3][5],d045,z3);
        const float iv = rcp_(1.0f + exp2_(z0));
        const float fv = rcp_(1.0f + exp2_(z1));
        const float gv = fmaf(2.0f, rcp_(1.0f + exp2_(z2)), -1.0f);
        const float ov = rcp_(1.0f + exp2_(z3));
        cc0 = fmaf(fv, cc0, iv*gv);
        hn0 = ov * tanh_(cc0);
        const float t0=swzbc<0>(hn0), t1=swzbc<1>(hn0), t2=swzbc<2>(hn0),
                    t3=swzbc<3>(hn0), t4=swzbc<4>(hn0), t5=swzbc<5>(hn0);
        d001=pkrtz(t0,t1); d023=pkrtz(t2,t3); d045=pkrtz(t4,t5);
    };
    auto STEP1 = [&](u32 r0d, u32 r1d, u32 r2d){
        float z0=cEb1[0], z1=cEb1[1], z2=cEb1[2], z3=cEb1[3];
        z0=dot2u(wd1[0][0],d001,z0); z0=dot2u(wd1[0][1],d023,z0); z0=dot2u(wd1[0][2],d045,z0);
        z0=dot2u(wd1[0][3],r0d,z0); z0=dot2u(wd1[0][4],r1d,z0); z0=dot2u(wd1[0][5],r2d,z0);
        z0=dot2u(wd1[0][6],d101,z0); z0=dot2u(wd1[0][7],d123,z0); z0=dot2u(wd1[0][8],d145,z0);
        z1=dot2u(wd1[1][0],d001,z1); z1=dot2u(wd1[1][1],d023,z1); z1=dot2u(wd1[1][2],d045,z1);
        z1=dot2u(wd1[1][3],r0d,z1); z1=dot2u(wd1[1][4],r1d,z1); z1=dot2u(wd1[1][5],r2d,z1);
        z1=dot2u(wd1[1][6],d101,z1); z1=dot2u(wd1[1][7],d123,z1); z1=dot2u(wd1[1][8],d145,z1);
        z2=dot2u(wd1[2][0],d001,z2); z2=dot2u(wd1[2][1],d023,z2); z2=dot2u(wd1[2][2],d045,z2);
        z2=dot2u(wd1[2][3],r0d,z2); z2=dot2u(wd1[2][4],r1d,z2); z2=dot2u(wd1[2][5],r2d,z2);
        z2=dot2u(wd1[2][6],d101,z2); z2=dot2u(wd1[2][7],d123,z2); z2=dot2u(wd1[2][8],d145,z2);
        z3=dot2u(wd1[3][0],d001,z3); z3=dot2u(wd1[3][1],d023,z3); z3=dot2u(wd1[3][2],d045,z3);
        z3=dot2u(wd1[3][3],r0d,z3); z3=dot2u(wd1[3][4],r1d,z3); z3=dot2u(wd1[3][5],r2d,z3);
        z3=dot2u(wd1[3][6],d101,z3); z3=dot2u(wd1[3][7],d123,z3); z3=dot2u(wd1[3][8],d145,z3);
        const float iv = rcp_(1.0f + exp2_(z0));
        const float fv = rcp_(1.0f + exp2_(z1));
        const float gv = fmaf(2.0f, rcp_(1.0f + exp2_(z2)), -1.0f);
        const float ov = rcp_(1.0f + exp2_(z3));
        cc1 = fmaf(fv, cc1, iv*gv);
        hn1 = ov * tanh_(cc1);
        const float t0=swzbc<0>(hn1), t1=swzbc<1>(hn1), t2=swzbc<2>(hn1),
                    t3=swzbc<3>(hn1), t4=swzbc<4>(hn1), t5=swzbc<5>(hn1);
        d101=pkrtz(t0,t1); d123=pkrtz(t2,t3); d145=pkrtz(t4,t5);
    };

    f32x4 xA[3], xB[3];
    u32x2 RA[3], RB[3];
    auto ldg = [&](int p, f32x4* d){
        const f32x4* q = (const f32x4*)(xb + (size_t)p*48);
        d[0]=q[0]; d[1]=q[1]; d[2]=q[2];
    };
    auto ldr = [&](int p, u32x2* R){
        const u32x2* r = (const u32x2*)(rp + (size_t)p*tstr);
        R[0]=r[0]; R[1]=r[1]; R[2]=r[2];
    };

    auto GROUP = [&](const f32x4* d, const u32x2* R){
        STEP0(pkrtz(d[0].x,d[0].y), pkrtz(d[0].z,d[0].w), pkrtz(d[1].x,d[1].y));
        STEP1(R[0].x, R[1].x, R[2].x);
        STEP0(pkrtz(d[1].z,d[1].w), pkrtz(d[2].x,d[2].y), pkrtz(d[2].z,d[2].w));
        STEP1(R[0].y, R[1].y, R[2].y);
    };

    ldg(0, xA); ldr(0, RA);
    ldg(1, xB); ldr(1, RB);
    for (int p=0; p<NT/2; p+=2){
        GROUP(xA, RA);
        { int pn=p+2; if (pn>NT/2-1) pn=NT/2-1; ldg(pn, xA); ldr(pn, RA); }
        GROUP(xB, RB);
        { int pn=p+3; if (pn>NT/2-1) pn=NT/2-1; ldg(pn, xB); ldr(pn, RB); }
    }
    // hn0 = f0[511] (f32), hn1 = f1[511] (f32); RB holds r0 pair 255.

    // ---- l0[511] as f32: f0 via swzbc(hn0), r0 via RB odd dwords ----
    float v[12];
    v[0]=swzbc<0>(hn0); v[1]=swzbc<1>(hn0); v[2]=swzbc<2>(hn0);
    v[3]=swzbc<3>(hn0); v[4]=swzbc<4>(hn0); v[5]=swzbc<5>(hn0);
#pragma unroll
    for (int k=0;k<3;++k){
        v[6+2*k] = upk_lo(RB[k].y);
        v[7+2*k] = upk_hi(RB[k].y);
    }

    // ---- r1: single reverse-direction step at t = NT-1 (f32 math) ----
    const int base3 = 3*(NB*6) + b*6;
    float hr6[6];
#pragma unroll
    for (int k=0;k<6;++k) hr6[k] = h0[base3 + k];
    float cr = c0[base3 + jj];

    float zr[4];
#pragma unroll
    for (int g=0; g<4; ++g){
        const int row = g*6 + jj;
        float acc = b1b[row];
#pragma unroll
        for (int k=0;k<12;++k) acc = fmaf(W1b[row*12+k], v[k], acc);
#pragma unroll
        for (int k=0;k<6;++k)  acc = fmaf(U1b[row*6+k], hr6[k], acc);
        zr[g] = acc;
    }
    {
        const float iv = sigm(zr[0]);
        const float fv = sigm(zr[1]);
        const float gv = tanh_(zr[2]);
        cr = fmaf(fv, cr, iv*gv);
    }
    const float hrv = sigm(zr[3]) * tanh_(cr);

    // ---- head: out[b][j] = fcb[j] + fcw[j] . relu([h1; r1]) ----
    float u[12];
    u[0]=fmaxf(swzbc<0>(hn1),0.f); u[1]=fmaxf(swzbc<1>(hn1),0.f); u[2]=fmaxf(swzbc<2>(hn1),0.f);
    u[3]=fmaxf(swzbc<3>(hn1),0.f); u[4]=fmaxf(swzbc<4>(hn1),0.f); u[5]=fmaxf(swzbc<5>(hn1),0.f);
    u[6]=fmaxf(swzbc<0>(hrv),0.f); u[7]=fmaxf(swzbc<1>(hrv),0.f); u[8]=fmaxf(swzbc<2>(hrv),0.f);
    u[9]=fmaxf(swzbc<3>(hrv),0.f); u[10]=fmaxf(swzbc<4>(hrv),0.f); u[11]=fmaxf(swzbc<5>(hrv),0.f);
    if (j < 6){
        float acc = fcb[j];
#pragma unroll
        for (int k=0;k<12;++k) acc = fmaf(fcw[j*12+k], u[k], acc);
        out[b*6 + j] = acc;
    }
}

extern "C" void kernel_launch(void* const* d_in, const int* in_sizes, int n_in,
                              void* d_out, int out_size, void* d_ws, size_t ws_size,
                              hipStream_t stream)
{
    (void)in_sizes; (void)n_in; (void)out_size; (void)ws_size;
    const float* x    = (const float*)d_in[0];
    const float* h0   = (const float*)d_in[1];
    const float* c0   = (const float*)d_in[2];
    const float* W0f  = (const float*)d_in[3];
    const float* U0f  = (const float*)d_in[4];
    const float* b0f  = (const float*)d_in[5];
    const float* W0b  = (const float*)d_in[6];
    const float* U0b  = (const float*)d_in[7];
    const float* b0b  = (const float*)d_in[8];
    const float* W1f  = (const float*)d_in[9];
    const float* U1f  = (const float*)d_in[10];
    const float* b1f  = (const float*)d_in[11];
    const float* W1b  = (const float*)d_in[12];
    const float* U1b  = (const float*)d_in[13];
    const float* b1b  = (const float*)d_in[14];
    const float* fcw  = (const float*)d_in[15];
    const float* fcb  = (const float*)d_in[16];
    float* out = (float*)d_out;
    char* ws = (char*)d_ws;

    char* bbuf = ws;   // (NT/2)*NB*24 = 50.3 MB

    lstm_l0b<<<dim3(1024), dim3(64), 0, stream>>>(x, h0, c0, W0b, U0b, b0b, bbuf);
    lstm_f01<<<dim3(1024), dim3(64), 0, stream>>>(bbuf, x, h0, c0,
        W0f, U0f, b0f, W1f, U1f, b1f, W1b, U1b, b1b, fcw, fcb, out);
}

// Round 20
// 271.757 us; speedup vs baseline: 1.0781x; 1.0544x over previous
//
#include <hip/hip_runtime.h>

#define NB 8192
#define NT 512

typedef unsigned int u32;
typedef unsigned short u16;
typedef float f32x4 __attribute__((ext_vector_type(4)));
typedef u32 u32x2 __attribute__((ext_vector_type(2)));
typedef _Float16 h16x2 __attribute__((ext_vector_type(2)));

__device__ __forceinline__ float rcp_(float x){ return __builtin_amdgcn_rcpf(x); }
__device__ __forceinline__ float exp2_(float x){ return __builtin_amdgcn_exp2f(x); }
__device__ __forceinline__ float tanh_(float x){ return 1.0f - 2.0f*rcp_(1.0f + exp2_(2.88539008177792681f*x)); }
__device__ __forceinline__ float sigm(float x){ return rcp_(1.0f + exp2_(-1.44269504088896341f*x)); }

#define PINF(v)  asm volatile("" : "+v"(v))

// quad_perm xor1: [1,0,3,2]
#define QP_XOR1 0xB1
__device__ __forceinline__ float dpp_xor1(float x){
    return __int_as_float(__builtin_amdgcn_update_dpp(0, __float_as_int(x), QP_XOR1, 0xF, 0xF, true));
}

// Broadcast lane (group8_base + J) to all 8 lanes of the group (validated R17).
template<int J>
__device__ __forceinline__ float swzbc(float x){
    return __int_as_float(__builtin_amdgcn_ds_swizzle(__float_as_int(x), (J<<5)|0x18));
}
template<int J>
__device__ __forceinline__ u32 swzbcu(u32 x){
    return (u32)__builtin_amdgcn_ds_swizzle((int)x, (J<<5)|0x18);
}

__device__ __forceinline__ float upkh(u16 v){ _Float16 h; __builtin_memcpy(&h,&v,2); return (float)h; }
__device__ __forceinline__ float upk_lo(u32 v){ return upkh((u16)(v&0xffffu)); }
__device__ __forceinline__ float upk_hi(u32 v){ return upkh((u16)(v>>16)); }
__device__ __forceinline__ u32 pkrtz(float a, float b){
    auto p = __builtin_amdgcn_cvt_pkrtz(a, b);
    return __builtin_bit_cast(u32, p);
}
__device__ __forceinline__ float dot2f(h16x2 a, h16x2 b, float c){
#if __has_builtin(__builtin_amdgcn_fdot2)
    return __builtin_amdgcn_fdot2(a, b, c, false);
#else
    return fmaf((float)a.x, (float)b.x, fmaf((float)a.y, (float)b.y, c));
#endif
}
__device__ __forceinline__ float dot2u(u32 w, u32 d, float c){
    return dot2f(__builtin_bit_cast(h16x2, w), __builtin_bit_cast(h16x2, d), c);
}

// ---------------------------------------------------------------------------
// Lane-local-gates layout (validated R17): 8 lanes/seq; lane j owns hidden
// unit jj; all 4 gates lane-local. NEW broadcast block (this round):
//   hp  = pkrtz(hn, dpp_xor1(hn))      // even lanes: (h_even, h_odd) pairs
//   d01 = swzbcu<0>(hp); d23 = swzbcu<2>(hp); d45 = swzbcu<4>(hp)
// 5 ops replacing 6 float-swizzles + 3 pkrtz (9 ops).
// Buffer per (t-pair, seq): [h01@E, h01@O, h23@E, h23@O, h45@E, h45@O] fp16.
// ---------------------------------------------------------------------------

#define BCAST(hn, d01, d23, d45) do{                 \
    const float _hx = dpp_xor1(hn);                  \
    const u32 _hp = pkrtz((hn), _hx);                \
    d01 = swzbcu<0>(_hp);                            \
    d23 = swzbcu<2>(_hp);                            \
    d45 = swzbcu<4>(_hp);                            \
}while(0)

// Layer 0, both directions. 2048 blocks x 64 = 2048 waves (2/SIMD).
__global__ __launch_bounds__(64)
__attribute__((amdgpu_waves_per_eu(2,2)))
void lstm_l0v2(
    const float* __restrict__ x,
    const float* __restrict__ h0, const float* __restrict__ c0,
    const float* __restrict__ Wf, const float* __restrict__ Uf, const float* __restrict__ bf,
    const float* __restrict__ Wb, const float* __restrict__ Ub, const float* __restrict__ bbv,
    char* __restrict__ fbuf, char* __restrict__ bbuf)
{
    const int l  = threadIdx.x;
    const int j  = l & 7;
    const int jj = (j < 6) ? j : (j - 2);
    const int e  = blockIdx.x*8 + (l >> 3);
    const int b  = e & (NB-1);
    const int dir = e >> 13;

    const float* W  = dir ? Wb  : Wf;
    const float* U  = dir ? Ub  : Uf;
    const float* bi = dir ? bbv : bf;

    u32 wd[4][6]; float cEb[4];
#pragma unroll
    for (int g=0; g<4; ++g){
        const int row = g*6 + jj;
        const float cs = (g==2) ? -2.88539008177792681f : -1.44269504088896341f;
#pragma unroll
        for (int k=0;k<3;++k) wd[g][k]   = pkrtz(cs*W[row*6+2*k], cs*W[row*6+2*k+1]);
#pragma unroll
        for (int k=0;k<3;++k) wd[g][3+k] = pkrtz(cs*U[row*6+2*k], cs*U[row*6+2*k+1]);
        cEb[g] = cs * bi[row];
    }
#pragma unroll
    for (int g=0; g<4; ++g){
#pragma unroll
        for (int k=0;k<6;++k) PINF(wd[g][k]);
        PINF(cEb[g]);
    }

    float cc = c0[dir*(NB*6) + b*6 + jj];
    float hn = h0[dir*(NB*6) + b*6 + jj];
    u32 d01, d23, d45;
    BCAST(hn, d01, d23, d45);

    const char* xb = (const char*)(x + (size_t)b*(NT*6));
    char* obase = (dir ? bbuf : fbuf) + (size_t)b*24 + j*8;   // used when j<3
    const size_t tstr = (size_t)NB*24;

    auto STEP = [&](u32 px0, u32 px1, u32 px2){
        float z0=cEb[0], z1=cEb[1], z2=cEb[2], z3=cEb[3];
        z0=dot2u(wd[0][0],px0,z0); z0=dot2u(wd[0][1],px1,z0); z0=dot2u(wd[0][2],px2,z0);
        z0=dot2u(wd[0][3],d01,z0); z0=dot2u(wd[0][4],d23,z0); z0=dot2u(wd[0][5],d45,z0);
        z1=dot2u(wd[1][0],px0,z1); z1=dot2u(wd[1][1],px1,z1); z1=dot2u(wd[1][2],px2,z1);
        z1=dot2u(wd[1][3],d01,z1); z1=dot2u(wd[1][4],d23,z1); z1=dot2u(wd[1][5],d45,z1);
        z2=dot2u(wd[2][0],px0,z2); z2=dot2u(wd[2][1],px1,z2); z2=dot2u(wd[2][2],px2,z2);
        z2=dot2u(wd[2][3],d01,z2); z2=dot2u(wd[2][4],d23,z2); z2=dot2u(wd[2][5],d45,z2);
        z3=dot2u(wd[3][0],px0,z3); z3=dot2u(wd[3][1],px1,z3); z3=dot2u(wd[3][2],px2,z3);
        z3=dot2u(wd[3][3],d01,z3); z3=dot2u(wd[3][4],d23,z3); z3=dot2u(wd[3][5],d45,z3);
        const float iv = rcp_(1.0f + exp2_(z0));
        const float fv = rcp_(1.0f + exp2_(z1));
        const float gv = fmaf(2.0f, rcp_(1.0f + exp2_(z2)), -1.0f);
        const float ov = rcp_(1.0f + exp2_(z3));
        cc = fmaf(fv, cc, iv*gv);
        hn = ov * tanh_(cc);
        BCAST(hn, d01, d23, d45);
    };

    f32x4 xA[3], xB[3];
    auto ldg = [&](int p, f32x4* d){
        const f32x4* q = (const f32x4*)(xb + (size_t)p*48);
        d[0]=q[0]; d[1]=q[1]; d[2]=q[2];
    };

    auto GROUP = [&](const f32x4* d, int p){
        u32 e0,e1,e2,o0,o1,o2;
        if (!dir){
            STEP(pkrtz(d[0].x,d[0].y), pkrtz(d[0].z,d[0].w), pkrtz(d[1].x,d[1].y));
            e0=d01; e1=d23; e2=d45;
            STEP(pkrtz(d[1].z,d[1].w), pkrtz(d[2].x,d[2].y), pkrtz(d[2].z,d[2].w));
            o0=d01; o1=d23; o2=d45;
        } else {
            STEP(pkrtz(d[1].z,d[1].w), pkrtz(d[2].x,d[2].y), pkrtz(d[2].z,d[2].w));
            o0=d01; o1=d23; o2=d45;
            STEP(pkrtz(d[0].x,d[0].y), pkrtz(d[0].z,d[0].w), pkrtz(d[1].x,d[1].y));
            e0=d01; e1=d23; e2=d45;
        }
        if (j < 3){
            const u32 se = (j==0)?e0:((j==1)?e1:e2);
            const u32 so = (j==0)?o0:((j==1)?o1:o2);
            u32x2 v; v.x=se; v.y=so;
            *(u32x2*)(obase + (size_t)p*tstr) = v;
        }
    };

    const int dp = dir ? -1 : 1;
    int p = dir ? (NT/2-1) : 0;
    {
        int p1 = p+dp; p1 = p1<0?0:(p1>NT/2-1?NT/2-1:p1);
        ldg(p, xA); ldg(p1, xB);
    }
    for (int it=0; it<NT/2; it+=2){
        GROUP(xA, p);
        { int pn=p+2*dp; pn = pn<0?0:(pn>NT/2-1?NT/2-1:pn); ldg(pn, xA); }
        p += dp;
        GROUP(xB, p);
        { int pn=p+2*dp; pn = pn<0?0:(pn>NT/2-1?NT/2-1:pn); ldg(pn, xB); }
        p += dp;
    }
}

// Layer 1 forward scan + r1 single step + FC head. 1024 blocks x 64.
__global__ __launch_bounds__(64)
__attribute__((amdgpu_waves_per_eu(1,1)))
void lstm_l1v2(
    const char* __restrict__ fbuf, const char* __restrict__ bbuf,
    const float* __restrict__ h0, const float* __restrict__ c0,
    const float* __restrict__ W1f, const float* __restrict__ U1f, const float* __restrict__ b1f,
    const float* __restrict__ W1b, const float* __restrict__ U1b, const float* __restrict__ b1b,
    const float* __restrict__ fcw, const float* __restrict__ fcb,
    float* __restrict__ out)
{
    const int l  = threadIdx.x;
    const int j  = l & 7;
    const int jj = (j < 6) ? j : (j - 2);
    const int b  = blockIdx.x*8 + (l >> 3);

    u32 wd1[4][9]; float cEb[4];
#pragma unroll
    for (int g=0; g<4; ++g){
        const int row = g*6 + jj;
        const float cs = (g==2) ? -2.88539008177792681f : -1.44269504088896341f;
#pragma unroll
        for (int k=0;k<3;++k) wd1[g][k]   = pkrtz(cs*W1f[row*12+2*k],   cs*W1f[row*12+2*k+1]);
#pragma unroll
        for (int k=0;k<3;++k) wd1[g][3+k] = pkrtz(cs*W1f[row*12+6+2*k], cs*W1f[row*12+6+2*k+1]);
#pragma unroll
        for (int k=0;k<3;++k) wd1[g][6+k] = pkrtz(cs*U1f[row*6+2*k],    cs*U1f[row*6+2*k+1]);
        cEb[g] = cs * b1f[row];
    }
#pragma unroll
    for (int g=0; g<4; ++g){
#pragma unroll
        for (int k=0;k<9;++k) PINF(wd1[g][k]);
        PINF(cEb[g]);
    }

    float cc = c0[2*(NB*6) + b*6 + jj];
    float hn = h0[2*(NB*6) + b*6 + jj];
    u32 d01, d23, d45;
    BCAST(hn, d01, d23, d45);

    const char* fp = fbuf + (size_t)b*24;
    const char* rp = bbuf + (size_t)b*24;
    const size_t tstr = (size_t)NB*24;

    auto STEP = [&](u32 f0d, u32 f1d, u32 f2d, u32 r0d, u32 r1d, u32 r2d){
        float z0=cEb[0], z1=cEb[1], z2=cEb[2], z3=cEb[3];
        z0=dot2u(wd1[0][0],f0d,z0); z0=dot2u(wd1[0][1],f1d,z0); z0=dot2u(wd1[0][2],f2d,z0);
        z0=dot2u(wd1[0][3],r0d,z0); z0=dot2u(wd1[0][4],r1d,z0); z0=dot2u(wd1[0][5],r2d,z0);
        z0=dot2u(wd1[0][6],d01,z0); z0=dot2u(wd1[0][7],d23,z0); z0=dot2u(wd1[0][8],d45,z0);
        z1=dot2u(wd1[1][0],f0d,z1); z1=dot2u(wd1[1][1],f1d,z1); z1=dot2u(wd1[1][2],f2d,z1);
        z1=dot2u(wd1[1][3],r0d,z1); z1=dot2u(wd1[1][4],r1d,z1); z1=dot2u(wd1[1][5],r2d,z1);
        z1=dot2u(wd1[1][6],d01,z1); z1=dot2u(wd1[1][7],d23,z1); z1=dot2u(wd1[1][8],d45,z1);
        z2=dot2u(wd1[2][0],f0d,z2); z2=dot2u(wd1[2][1],f1d,z2); z2=dot2u(wd1[2][2],f2d,z2);
        z2=dot2u(wd1[2][3],r0d,z2); z2=dot2u(wd1[2][4],r1d,z2); z2=dot2u(wd1[2][5],r2d,z2);
        z2=dot2u(wd1[2][6],d01,z2); z2=dot2u(wd1[2][7],d23,z2); z2=dot2u(wd1[2][8],d45,z2);
        z3=dot2u(wd1[3][0],f0d,z3); z3=dot2u(wd1[3][1],f1d,z3); z3=dot2u(wd1[3][2],f2d,z3);
        z3=dot2u(wd1[3][3],r0d,z3); z3=dot2u(wd1[3][4],r1d,z3); z3=dot2u(wd1[3][5],r2d,z3);
        z3=dot2u(wd1[3][6],d01,z3); z3=dot2u(wd1[3][7],d23,z3); z3=dot2u(wd1[3][8],d45,z3);
        const float iv = rcp_(1.0f + exp2_(z0));
        const float fv = rcp_(1.0f + exp2_(z1));
        const float gv = fmaf(2.0f, rcp_(1.0f + exp2_(z2)), -1.0f);
        const float ov = rcp_(1.0f + exp2_(z3));
        cc = fmaf(fv, cc, iv*gv);
        hn = ov * tanh_(cc);
        BCAST(hn, d01, d23, d45);
    };

    u32x2 FA[3], RA[3], FB[3], RB[3];
    auto ldp = [&](int p, u32x2* F, u32x2* R){
        const u32x2* f = (const u32x2*)(fp + (size_t)p*tstr);
        const u32x2* r = (const u32x2*)(rp + (size_t)p*tstr);
        F[0]=f[0]; F[1]=f[1]; F[2]=f[2];
        R[0]=r[0]; R[1]=r[1]; R[2]=r[2];
    };
    auto GROUP = [&](const u32x2* F, const u32x2* R){
        STEP(F[0].x, F[1].x, F[2].x, R[0].x, R[1].x, R[2].x);
        STEP(F[0].y, F[1].y, F[2].y, R[0].y, R[1].y, R[2].y);
    };

    ldp(0, FA, RA); ldp(1, FB, RB);
    for (int p=0; p<NT/2; p+=2){
        GROUP(FA, RA);
        { int pn=p+2; pn = pn>NT/2-1?NT/2-1:pn; ldp(pn, FA, RA); }
        GROUP(FB, RB);
        { int pn=p+3; pn = pn>NT/2-1?NT/2-1:pn; ldp(pn, FB, RB); }
    }
    // hn = h1[511] (f32, lane j = hidden jj)

    // ---- l0[511] as f32 (odd dwords of pair 255) ----
    float v[12];
    {
        const char* f255 = fp + (size_t)(NT/2-1)*tstr;
        const char* r255 = rp + (size_t)(NT/2-1)*tstr;
#pragma unroll
        for (int k=0;k<3;++k){
            const u32 fd = *(const u32*)(f255 + k*8 + 4);
            const u32 rd = *(const u32*)(r255 + k*8 + 4);
            v[2*k]   = upk_lo(fd);  v[2*k+1]   = upk_hi(fd);
            v[6+2*k] = upk_lo(rd);  v[6+2*k+1] = upk_hi(rd);
        }
    }

    // ---- r1: single reverse-direction step at t = NT-1 (f32 math) ----
    const int base3 = 3*(NB*6) + b*6;
    float hr6[6];
#pragma unroll
    for (int k=0;k<6;++k) hr6[k] = h0[base3 + k];
    float cr = c0[base3 + jj];

    float zr[4];
#pragma unroll
    for (int g=0; g<4; ++g){
        const int row = g*6 + jj;
        float acc = b1b[row];
#pragma unroll
        for (int k=0;k<12;++k) acc = fmaf(W1b[row*12+k], v[k], acc);
#pragma unroll
        for (int k=0;k<6;++k)  acc = fmaf(U1b[row*6+k], hr6[k], acc);
        zr[g] = acc;
    }
    {
        const float iv = sigm(zr[0]);
        const float fv = sigm(zr[1]);
        const float gv = tanh_(zr[2]);
        cr = fmaf(fv, cr, iv*gv);
    }
    const float hrv = sigm(zr[3]) * tanh_(cr);

    // ---- head: out[b][j] = fcb[j] + fcw[j] . relu([h1; r1]) ----
    float u[12];
    u[0]=fmaxf(swzbc<0>(hn),0.f); u[1]=fmaxf(swzbc<1>(hn),0.f); u[2]=fmaxf(swzbc<2>(hn),0.f);
    u[3]=fmaxf(swzbc<3>(hn),0.f); u[4]=fmaxf(swzbc<4>(hn),0.f); u[5]=fmaxf(swzbc<5>(hn),0.f);
    u[6]=fmaxf(swzbc<0>(hrv),0.f); u[7]=fmaxf(swzbc<1>(hrv),0.f); u[8]=fmaxf(swzbc<2>(hrv),0.f);
    u[9]=fmaxf(swzbc<3>(hrv),0.f); u[10]=fmaxf(swzbc<4>(hrv),0.f); u[11]=fmaxf(swzbc<5>(hrv),0.f);
    if (j < 6){
        float acc = fcb[j];
#pragma unroll
        for (int k=0;k<12;++k) acc = fmaf(fcw[j*12+k], u[k], acc);
        out[b*6 + j] = acc;
    }
}

extern "C" void kernel_launch(void* const* d_in, const int* in_sizes, int n_in,
                              void* d_out, int out_size, void* d_ws, size_t ws_size,
                              hipStream_t stream)
{
    (void)in_sizes; (void)n_in; (void)out_size; (void)ws_size;
    const float* x    = (const float*)d_in[0];
    const float* h0   = (const float*)d_in[1];
    const float* c0   = (const float*)d_in[2];
    const float* W0f  = (const float*)d_in[3];
    const float* U0f  = (const float*)d_in[4];
    const float* b0f  = (const float*)d_in[5];
    const float* W0b  = (const float*)d_in[6];
    const float* U0b  = (const float*)d_in[7];
    const float* b0b  = (const float*)d_in[8];
    const float* W1f  = (const float*)d_in[9];
    const float* U1f  = (const float*)d_in[10];
    const float* b1f  = (const float*)d_in[11];
    const float* W1b  = (const float*)d_in[12];
    const float* U1b  = (const float*)d_in[13];
    const float* b1b  = (const float*)d_in[14];
    const float* fcw  = (const float*)d_in[15];
    const float* fcb  = (const float*)d_in[16];
    float* out = (float*)d_out;
    char* ws = (char*)d_ws;

    char* fbuf = ws;
    char* bbuf = ws + (size_t)(NT/2)*NB*24;   // 2 x 50.3 MB

    lstm_l0v2<<<dim3(2048), dim3(64), 0, stream>>>(x, h0, c0, W0f, U0f, b0f, W0b, U0b, b0b, fbuf, bbuf);
    lstm_l1v2<<<dim3(1024), dim3(64), 0, stream>>>(fbuf, bbuf, h0, c0,
        W1f, U1f, b1f, W1b, U1b, b1b, fcw, fcb, out);
}